// Round 4
// baseline (360.859 us; speedup 1.0000x reference)
//
#include <hip/hip_runtime.h>

typedef unsigned int u32;
typedef unsigned short u16;
typedef u16 u16x4 __attribute__((ext_vector_type(4)));
typedef u16 u16x8 __attribute__((ext_vector_type(8)));
typedef __bf16 bf16x8 __attribute__((ext_vector_type(8)));
typedef float f32x4 __attribute__((ext_vector_type(4)));

#define LDK 136   // padded LDS leading dim (elems): 16B-aligned rows
#define MFMA(a, b, c) __builtin_amdgcn_mfma_f32_16x16x32_bf16(a, b, c, 0, 0, 0)

__device__ __forceinline__ u16 f2b(float f) {
  u32 u = __builtin_bit_cast(u32, f);
  u = (u + 0x7fffu + ((u >> 16) & 1u)) >> 16;
  return (u16)u;
}
__device__ __forceinline__ float b2f(u16 h) {
  u32 u = ((u32)h) << 16;
  return __builtin_bit_cast(float, u);
}

// ---------------- weight prep: wT[m][d][c] = bf16(W_m[c][d]) ----------------
__global__ void wprep(const float* __restrict__ Wq, const float* __restrict__ Wk,
                      const float* __restrict__ Wv, const float* __restrict__ Ws,
                      u16* __restrict__ wT) {
  const float* srcs[4] = {Wq, Wk, Wv, Ws};
  const float* s = srcs[blockIdx.x];
  u16* d = wT + (size_t)blockIdx.x * 16384;
  for (int idx = threadIdx.x; idx < 16384; idx += 256) {
    int i = idx >> 7, j = idx & 127;   // W[i=c_in][j=c_out]
    d[j * 128 + i] = f2b(s[idx]);
  }
}

// ---------------- QKV: per (b,h) row, 3x [128w x 128c x 128k] GEMM + ReLU ----------------
// W fragments live in registers (global/L2 loads) -> LDS = 68 KB -> 2 blocks/CU
__global__ __launch_bounds__(256, 2)
void qkv_kernel(const float* __restrict__ x1, const float* __restrict__ x2,
                const u16* __restrict__ wT,
                u16* __restrict__ q_t, u16* __restrict__ k_t, u16* __restrict__ v_t) {
  __shared__ u16 Xs[128 * LDK];   // x tile [w][c] (bf16); X1 for m=0,1; X2 for m=2
  __shared__ u16 ST[128 * LDK];   // output stage [c][w]

  const int t = threadIdx.x;
  const int bh = blockIdx.x;
  const int b = bh >> 7, h = bh & 127;
  const size_t pixbase = (size_t)bh * 16384;
  const size_t obase = (size_t)b * 2097152 + (size_t)h * 128;

#pragma unroll
  for (int j = 0; j < 8; ++j) {
    int lin = j * 256 + t;
    int w = lin >> 4, c0 = (lin & 15) << 3;
    f32x4 a0 = *(const f32x4*)&x1[pixbase + lin * 8];
    f32x4 a1 = *(const f32x4*)&x1[pixbase + lin * 8 + 4];
    u16x8 p;
#pragma unroll
    for (int i = 0; i < 4; ++i) { p[i] = f2b(a0[i]); p[4 + i] = f2b(a1[i]); }
    *(u16x8*)&Xs[w * LDK + c0] = p;
  }
  __syncthreads();   // X1 staging visible to all waves before m=0 MFMA (R3 bug: was missing)

  const int lane = t & 63, wave = t >> 6;
  const int lrow = lane & 15, lq = lane >> 4;
  const int nstrip = wave * 32;

  u16* outs[3] = {q_t, k_t, v_t};

  for (int m = 0; m < 3; ++m) {
    // B fragments straight from global (L2-hot, shared by all blocks)
    const u16* wb = wT + (size_t)m * 16384;
    bf16x8 w0[4], w1[4];
#pragma unroll
    for (int kk = 0; kk < 4; ++kk) {
      int ko = kk * 32 + lq * 8;
      w0[kk] = *(const bf16x8*)&wb[(nstrip + lrow) * 128 + ko];
      w1[kk] = *(const bf16x8*)&wb[(nstrip + 16 + lrow) * 128 + ko];
    }

    if (m == 2) {  // X1 dead (all waves past m=1 post-MFMA barrier) -> overwrite with X2
#pragma unroll
      for (int j = 0; j < 8; ++j) {
        int lin = j * 256 + t;
        int w = lin >> 4, c0 = (lin & 15) << 3;
        f32x4 a0 = *(const f32x4*)&x2[pixbase + lin * 8];
        f32x4 a1 = *(const f32x4*)&x2[pixbase + lin * 8 + 4];
        u16x8 p;
#pragma unroll
        for (int i = 0; i < 4; ++i) { p[i] = f2b(a0[i]); p[4 + i] = f2b(a1[i]); }
        *(u16x8*)&Xs[w * LDK + c0] = p;
      }
      __syncthreads();  // X2 visible to all before MFMA
    }

    f32x4 acc[8][2];
#pragma unroll
    for (int mt = 0; mt < 8; ++mt) {
      acc[mt][0] = (f32x4){0.f, 0.f, 0.f, 0.f};
      acc[mt][1] = (f32x4){0.f, 0.f, 0.f, 0.f};
    }
#pragma unroll
    for (int kk = 0; kk < 4; ++kk) {
      int ko = kk * 32 + lq * 8;
#pragma unroll
      for (int mt = 0; mt < 8; ++mt) {
        bf16x8 a = *(const bf16x8*)&Xs[(mt * 16 + lrow) * LDK + ko];
        acc[mt][0] = MFMA(a, w0[kk], acc[mt][0]);
        acc[mt][1] = MFMA(a, w1[kk], acc[mt][1]);
      }
    }
    __syncthreads();  // all Xs reads done; also orders prev iter's ST reads vs ST write below

    // stage with ReLU into ST[c][w] (D: col=lane&15 -> c, row=lq*4+r -> w)
#pragma unroll
    for (int mt = 0; mt < 8; ++mt) {
      int w0i = mt * 16 + lq * 4;
#pragma unroll
      for (int nt = 0; nt < 2; ++nt) {
        int c = nstrip + nt * 16 + lrow;
        u16x4 p;
#pragma unroll
        for (int r = 0; r < 4; ++r) p[r] = f2b(fmaxf(acc[mt][nt][r], 0.f));
        *(u16x4*)&ST[c * LDK + w0i] = p;
      }
    }
    __syncthreads();

    u16* dst = outs[m];
    {
      int c = t >> 1, w0i = (t & 1) * 64;
#pragma unroll
      for (int j = 0; j < 8; ++j)
        *(u16x8*)&dst[obase + (size_t)c * 16384 + w0i + j * 8] =
            *(const u16x8*)&ST[c * LDK + w0i + j * 8];
    }
  }
}

// ---------------- attention: per (b,c), S^T = K Q^T, softmax over g, O^T = V^T P^T ----------------
// two time-multiplexed LDS buffers (68 KB) -> 2 blocks/CU
__global__ __launch_bounds__(256, 2)
void attn_kernel(u16* __restrict__ q_t, const u16* __restrict__ k_t,
                 const u16* __restrict__ v_t, const float* __restrict__ scale_p) {
  __shared__ u16 Ks[128 * LDK];   // K [g][w] -> V^T [w][g] -> O stage [h][w]
  __shared__ u16 QP[128 * LDK];   // Q [h][w] -> P [h][g]

  const int t = threadIdx.x;
  const size_t base = (size_t)blockIdx.x * 16384;

#pragma unroll
  for (int j = 0; j < 8; ++j) {
    int lin = j * 256 + t;
    int r = lin >> 4, c0 = (lin & 15) << 3;
    *(u16x8*)&QP[r * LDK + c0] = *(const u16x8*)&q_t[base + lin * 8];
    *(u16x8*)&Ks[r * LDK + c0] = *(const u16x8*)&k_t[base + lin * 8];
  }
  __syncthreads();

  const int lane = t & 63, wave = t >> 6;
  const int lrow = lane & 15, lq = lane >> 4;
  const int hstrip = wave * 32;
  const float scl = scale_p[0];

  // S^T[g][h]: A = Ks rows g, B^T = QP rows h
  f32x4 acc[8][2];
#pragma unroll
  for (int mt = 0; mt < 8; ++mt) {
    acc[mt][0] = (f32x4){0.f, 0.f, 0.f, 0.f};
    acc[mt][1] = (f32x4){0.f, 0.f, 0.f, 0.f};
  }
#pragma unroll
  for (int kk = 0; kk < 4; ++kk) {
    int ko = kk * 32 + lq * 8;
    bf16x8 b0 = *(const bf16x8*)&QP[(hstrip + lrow) * LDK + ko];
    bf16x8 b1 = *(const bf16x8*)&QP[(hstrip + 16 + lrow) * LDK + ko];
#pragma unroll
    for (int mt = 0; mt < 8; ++mt) {
      bf16x8 a = *(const bf16x8*)&Ks[(mt * 16 + lrow) * LDK + ko];
      acc[mt][0] = MFMA(a, b0, acc[mt][0]);
      acc[mt][1] = MFMA(a, b1, acc[mt][1]);
    }
  }

  // issue V loads now; latency hides under the register softmax
  const int g0 = (t & 15) * 8, w0v = (t >> 4) * 8;
  u16x8 vv[8];
#pragma unroll
  for (int i = 0; i < 8; ++i)
    vv[i] = *(const u16x8*)&v_t[base + (g0 + i) * 128 + w0v];

  // softmax over g (rows of S^T): per-lane 32 values + quad combine via shfl_xor 16/32
  float inv[2];
#pragma unroll
  for (int nt = 0; nt < 2; ++nt) {
    float mx = -1e30f;
#pragma unroll
    for (int mt = 0; mt < 8; ++mt)
#pragma unroll
      for (int r = 0; r < 4; ++r) {
        acc[mt][nt][r] *= scl;
        mx = fmaxf(mx, acc[mt][nt][r]);
      }
    mx = fmaxf(mx, __shfl_xor(mx, 16));
    mx = fmaxf(mx, __shfl_xor(mx, 32));
    float s = 0.f;
#pragma unroll
    for (int mt = 0; mt < 8; ++mt)
#pragma unroll
      for (int r = 0; r < 4; ++r) {
        float e = __expf(acc[mt][nt][r] - mx);
        acc[mt][nt][r] = e;
        s += e;
      }
    s += __shfl_xor(s, 16);
    s += __shfl_xor(s, 32);
    inv[nt] = 1.f / s;
  }
  __syncthreads();   // all S-MFMA reads of Ks and QP complete

  // V^T into Ks (register 8x8 transpose), P into QP [h][g]
#pragma unroll
  for (int j = 0; j < 8; ++j) {
    u16x8 tv;
#pragma unroll
    for (int i = 0; i < 8; ++i) tv[i] = vv[i][j];
    *(u16x8*)&Ks[(w0v + j) * LDK + g0] = tv;
  }
#pragma unroll
  for (int mt = 0; mt < 8; ++mt) {
    int gg0 = mt * 16 + lq * 4;
#pragma unroll
    for (int nt = 0; nt < 2; ++nt) {
      int hh = hstrip + nt * 16 + lrow;
      u16x4 p;
#pragma unroll
      for (int r = 0; r < 4; ++r) p[r] = f2b(acc[mt][nt][r] * inv[nt]);
      *(u16x4*)&QP[hh * LDK + gg0] = p;
    }
  }
  __syncthreads();

  // O^T[w][h]: A = Ks(V^T) rows w, B^T = QP(P) rows h
  f32x4 o[8][2];
#pragma unroll
  for (int mt = 0; mt < 8; ++mt) {
    o[mt][0] = (f32x4){0.f, 0.f, 0.f, 0.f};
    o[mt][1] = (f32x4){0.f, 0.f, 0.f, 0.f};
  }
#pragma unroll
  for (int kk = 0; kk < 4; ++kk) {
    int ko = kk * 32 + lq * 8;
    bf16x8 b0 = *(const bf16x8*)&QP[(hstrip + lrow) * LDK + ko];
    bf16x8 b1 = *(const bf16x8*)&QP[(hstrip + 16 + lrow) * LDK + ko];
#pragma unroll
    for (int mt = 0; mt < 8; ++mt) {
      bf16x8 a = *(const bf16x8*)&Ks[(mt * 16 + lrow) * LDK + ko];
      o[mt][0] = MFMA(a, b0, o[mt][0]);
      o[mt][1] = MFMA(a, b1, o[mt][1]);
    }
  }
  __syncthreads();  // all O-MFMA reads of Ks complete before restaging

  // stage O into Ks [h][w]
#pragma unroll
  for (int mt = 0; mt < 8; ++mt) {
    int w0i = mt * 16 + lq * 4;
#pragma unroll
    for (int nt = 0; nt < 2; ++nt) {
      int hh = hstrip + nt * 16 + lrow;
      u16x4 p;
#pragma unroll
      for (int r = 0; r < 4; ++r) p[r] = f2b(o[mt][nt][r]);
      *(u16x4*)&Ks[hh * LDK + w0i] = p;
    }
  }
  __syncthreads();

  {
    int hh = t >> 1, w0i = (t & 1) * 64;
#pragma unroll
    for (int j = 0; j < 8; ++j)
      *(u16x8*)&q_t[base + hh * 128 + w0i + j * 8] =
          *(const u16x8*)&Ks[hh * LDK + w0i + j * 8];
  }
}

// ---------------- final: s = o @ Ws + bs; sigmoid; BN; out = x1 + x2*g (fp32) ----------------
// Ws^T fragments from global/L2 -> LDS = 36 KB -> up to 4 blocks/CU
__global__ __launch_bounds__(256, 3)
void final_kernel(const u16* __restrict__ o_t, const u16* __restrict__ wsT,
                  const float* __restrict__ x1, const float* __restrict__ x2,
                  const float* __restrict__ bs, const float* __restrict__ gamma,
                  const float* __restrict__ beta, const float* __restrict__ mu,
                  const float* __restrict__ var, float* __restrict__ out) {
  __shared__ u16 Os[128 * LDK];   // o^T tile [w][c]; later g' stage [w][d]
  __shared__ float bnA[128], bnB[128], bsf[128];

  const int t = threadIdx.x;
  const int bh = blockIdx.x;
  const int b = bh >> 7, h = bh & 127;
  const size_t obase = (size_t)b * 2097152 + (size_t)h * 128;
  const size_t pixbase = (size_t)bh * 16384;

  if (t < 128) {
    float a = gamma[t] * rsqrtf(var[t] + 1e-3f);
    bnA[t] = a;
    bnB[t] = beta[t] - mu[t] * a;
    bsf[t] = bs[t];
  }
  {  // transpose-load o tile -> Os[w][c]
    int c0 = (t & 15) * 8, w0 = (t >> 4) * 8;
    u16 ov[8][8];
#pragma unroll
    for (int i = 0; i < 8; ++i)
      *(u16x8*)&ov[i][0] = *(const u16x8*)&o_t[obase + (size_t)(c0 + i) * 16384 + w0];
#pragma unroll
    for (int j = 0; j < 8; ++j) {
      u16x8 tv;
#pragma unroll
      for (int i = 0; i < 8; ++i) tv[i] = ov[i][j];
      *(u16x8*)&Os[(w0 + j) * LDK + c0] = tv;
    }
  }
  __syncthreads();

  const int lane = t & 63, wave = t >> 6;
  const int lrow = lane & 15, lq = lane >> 4;
  const int wstrip = wave * 32;

  // D[d][w] = sum_c WsT[d][c] * Os[w][c]; A fragments straight from global (L2-hot)
  f32x4 acc[8][2];
#pragma unroll
  for (int mt = 0; mt < 8; ++mt) {
    acc[mt][0] = (f32x4){0.f, 0.f, 0.f, 0.f};
    acc[mt][1] = (f32x4){0.f, 0.f, 0.f, 0.f};
  }
#pragma unroll
  for (int kk = 0; kk < 4; ++kk) {
    int ko = kk * 32 + lq * 8;
    bf16x8 b0 = *(const bf16x8*)&Os[(wstrip + lrow) * LDK + ko];
    bf16x8 b1 = *(const bf16x8*)&Os[(wstrip + 16 + lrow) * LDK + ko];
#pragma unroll
    for (int mt = 0; mt < 8; ++mt) {
      bf16x8 a = *(const bf16x8*)&wsT[(mt * 16 + lrow) * 128 + ko];
      acc[mt][0] = MFMA(a, b0, acc[mt][0]);
      acc[mt][1] = MFMA(a, b1, acc[mt][1]);
    }
  }
  __syncthreads();  // all waves done reading Os -> reuse as stage

  // epilogue: sigmoid + BN, stage g' into Os[w][d]
#pragma unroll
  for (int mt = 0; mt < 8; ++mt) {
    int d0 = mt * 16 + lq * 4;
#pragma unroll
    for (int nt = 0; nt < 2; ++nt) {
      int w = wstrip + nt * 16 + lrow;
      u16x4 p;
#pragma unroll
      for (int r = 0; r < 4; ++r) {
        int d = d0 + r;
        float sv = acc[mt][nt][r] + bsf[d];
        float sg = 1.f / (1.f + __expf(-sv));
        p[r] = f2b(bnA[d] * sg + bnB[d]);
      }
      *(u16x4*)&Os[w * LDK + d0] = p;
    }
  }
  __syncthreads();

  {  // gated residual in fp32
    int w = t >> 1, d0 = (t & 1) * 64;
#pragma unroll
    for (int j = 0; j < 8; ++j) {
      int d = d0 + j * 8;
      u16x8 g8 = *(const u16x8*)&Os[w * LDK + d];
      f32x4 a0 = *(const f32x4*)&x1[pixbase + w * 128 + d];
      f32x4 a1 = *(const f32x4*)&x1[pixbase + w * 128 + d + 4];
      f32x4 c0v = *(const f32x4*)&x2[pixbase + w * 128 + d];
      f32x4 c1v = *(const f32x4*)&x2[pixbase + w * 128 + d + 4];
      f32x4 r0, r1;
#pragma unroll
      for (int i = 0; i < 4; ++i) {
        r0[i] = a0[i] + c0v[i] * b2f(g8[i]);
        r1[i] = a1[i] + c1v[i] * b2f(g8[4 + i]);
      }
      *(f32x4*)&out[pixbase + w * 128 + d] = r0;
      *(f32x4*)&out[pixbase + w * 128 + d + 4] = r1;
    }
  }
}

extern "C" void kernel_launch(void* const* d_in, const int* in_sizes, int n_in,
                              void* d_out, int out_size, void* d_ws, size_t ws_size,
                              hipStream_t stream) {
  const float* x1 = (const float*)d_in[0];
  const float* x2 = (const float*)d_in[1];
  const float* Wq = (const float*)d_in[2];
  const float* Wk = (const float*)d_in[3];
  const float* Wv = (const float*)d_in[4];
  const float* Ws = (const float*)d_in[5];
  const float* bs = (const float*)d_in[6];
  const float* scale = (const float*)d_in[7];
  const float* gamma = (const float*)d_in[8];
  const float* beta = (const float*)d_in[9];
  const float* mu = (const float*)d_in[10];
  const float* var = (const float*)d_in[11];
  float* outp = (float*)d_out;

  // workspace (bf16 elems): q_t | k_t | v_t : [B][C][H][W], then 4 transposed weights
  u16* q_t = (u16*)d_ws;
  u16* k_t = q_t + 16777216;
  u16* v_t = k_t + 16777216;
  u16* wT = v_t + 16777216;  // 4 * 16384

  wprep<<<dim3(4), dim3(256), 0, stream>>>(Wq, Wk, Wv, Ws, wT);
  qkv_kernel<<<dim3(1024), dim3(256), 0, stream>>>(x1, x2, wT, q_t, k_t, v_t);
  attn_kernel<<<dim3(1024), dim3(256), 0, stream>>>(q_t, k_t, v_t, scale);
  final_kernel<<<dim3(1024), dim3(256), 0, stream>>>(q_t, wT + 3 * 16384, x1, x2, bs,
                                                     gamma, beta, mu, var, outp);
}

// Round 5
// 346.446 us; speedup vs baseline: 1.0416x; 1.0416x over previous
//
#include <hip/hip_runtime.h>

typedef unsigned int u32;
typedef unsigned short u16;
typedef u16 u16x4 __attribute__((ext_vector_type(4)));
typedef u16 u16x8 __attribute__((ext_vector_type(8)));
typedef __bf16 bf16x8 __attribute__((ext_vector_type(8)));
typedef float f32x4 __attribute__((ext_vector_type(4)));

#define LDK 136   // padded LDS leading dim (elems): 16B-aligned rows
#define MFMA(a, b, c) __builtin_amdgcn_mfma_f32_16x16x32_bf16(a, b, c, 0, 0, 0)

__device__ __forceinline__ u16 f2b(float f) {
  u32 u = __builtin_bit_cast(u32, f);
  u = (u + 0x7fffu + ((u >> 16) & 1u)) >> 16;
  return (u16)u;
}
__device__ __forceinline__ float b2f(u16 h) {
  u32 u = ((u32)h) << 16;
  return __builtin_bit_cast(float, u);
}

// ---------------- weight prep: wT[m][d][c] = bf16(W_m[c][d]) ----------------
__global__ void wprep(const float* __restrict__ Wq, const float* __restrict__ Wk,
                      const float* __restrict__ Wv, const float* __restrict__ Ws,
                      u16* __restrict__ wT) {
  const float* srcs[4] = {Wq, Wk, Wv, Ws};
  const float* s = srcs[blockIdx.x];
  u16* d = wT + (size_t)blockIdx.x * 16384;
  for (int idx = threadIdx.x; idx < 16384; idx += 256) {
    int i = idx >> 7, j = idx & 127;   // W[i=c_in][j=c_out]
    d[j * 128 + i] = f2b(s[idx]);
  }
}

// ---------------- QKV: block = (b,h,m); one 128x128x128 GEMM + ReLU ----------------
// 34 KB LDS -> 4 blocks/CU; single barrier; direct register->global stores
__global__ __launch_bounds__(256, 4)
void qkv_kernel(const float* __restrict__ x1, const float* __restrict__ x2,
                const u16* __restrict__ wT,
                u16* __restrict__ q_t, u16* __restrict__ k_t, u16* __restrict__ v_t) {
  __shared__ u16 Xs[128 * LDK];   // x tile [w][c] bf16

  const int t = threadIdx.x;
  const int bh = blockIdx.x;
  const int m = blockIdx.y;       // 0=q, 1=k, 2=v
  const int b = bh >> 7, h = bh & 127;
  const size_t pixbase = (size_t)bh * 16384;
  const size_t obase = (size_t)b * 2097152 + (size_t)h * 128;

  const float* xin = (m == 2) ? x2 : x1;
  u16* dst = (m == 0) ? q_t : (m == 1) ? k_t : v_t;

  const int lane = t & 63, wave = t >> 6;
  const int lrow = lane & 15, lq = lane >> 4;
  const int nstrip = wave * 32;

  // B fragments straight from global (L2-hot, shared by all blocks) — independent of LDS
  const u16* wb = wT + (size_t)m * 16384;
  bf16x8 w0[4], w1[4];
#pragma unroll
  for (int kk = 0; kk < 4; ++kk) {
    int ko = kk * 32 + lq * 8;
    w0[kk] = *(const bf16x8*)&wb[(nstrip + lrow) * 128 + ko];
    w1[kk] = *(const bf16x8*)&wb[(nstrip + 16 + lrow) * 128 + ko];
  }

  // stage x row-tile -> Xs[w][c] bf16
#pragma unroll
  for (int j = 0; j < 8; ++j) {
    int lin = j * 256 + t;
    int w = lin >> 4, c0 = (lin & 15) << 3;
    f32x4 a0 = *(const f32x4*)&xin[pixbase + lin * 8];
    f32x4 a1 = *(const f32x4*)&xin[pixbase + lin * 8 + 4];
    u16x8 p;
#pragma unroll
    for (int i = 0; i < 4; ++i) { p[i] = f2b(a0[i]); p[4 + i] = f2b(a1[i]); }
    *(u16x8*)&Xs[w * LDK + c0] = p;
  }
  __syncthreads();

  f32x4 acc[8][2];
#pragma unroll
  for (int mt = 0; mt < 8; ++mt) {
    acc[mt][0] = (f32x4){0.f, 0.f, 0.f, 0.f};
    acc[mt][1] = (f32x4){0.f, 0.f, 0.f, 0.f};
  }
#pragma unroll
  for (int kk = 0; kk < 4; ++kk) {
    int ko = kk * 32 + lq * 8;
#pragma unroll
    for (int mt = 0; mt < 8; ++mt) {
      bf16x8 a = *(const bf16x8*)&Xs[(mt * 16 + lrow) * LDK + ko];
      acc[mt][0] = MFMA(a, w0[kk], acc[mt][0]);
      acc[mt][1] = MFMA(a, w1[kk], acc[mt][1]);
    }
  }

  // direct store with ReLU: lane holds 4 consecutive w at fixed c -> 8 B stores
#pragma unroll
  for (int mt = 0; mt < 8; ++mt) {
    int w0i = mt * 16 + lq * 4;
#pragma unroll
    for (int nt = 0; nt < 2; ++nt) {
      int c = nstrip + nt * 16 + lrow;
      u16x4 p;
#pragma unroll
      for (int r = 0; r < 4; ++r) p[r] = f2b(fmaxf(acc[mt][nt][r], 0.f));
      *(u16x4*)&dst[obase + (size_t)c * 16384 + w0i] = p;
    }
  }
}

// ---------------- attention: per (b,c), S^T = K Q^T, softmax over g, O^T = V^T P^T ----------------
// Q fragments from global regs; Ks: K -> V^T; Ps: P. 3 barriers; direct O store.
__global__ __launch_bounds__(256, 2)
void attn_kernel(u16* __restrict__ q_t, const u16* __restrict__ k_t,
                 const u16* __restrict__ v_t, const float* __restrict__ scale_p) {
  __shared__ u16 Ks[128 * LDK];   // K [g][w] -> V^T [w][g]
  __shared__ u16 Ps[128 * LDK];   // P [h][g]

  const int t = threadIdx.x;
  const size_t base = (size_t)blockIdx.x * 16384;

  const int lane = t & 63, wave = t >> 6;
  const int lrow = lane & 15, lq = lane >> 4;
  const int hstrip = wave * 32;
  const float scl = scale_p[0];

  // Q fragments (per-wave-private rows) straight from global
  bf16x8 q0[4], q1[4];
#pragma unroll
  for (int kk = 0; kk < 4; ++kk) {
    int ko = kk * 32 + lq * 8;
    q0[kk] = *(const bf16x8*)&q_t[base + (hstrip + lrow) * 128 + ko];
    q1[kk] = *(const bf16x8*)&q_t[base + (hstrip + 16 + lrow) * 128 + ko];
  }
  // V into regs (transposed later); K into LDS
  const int g0 = (t & 15) * 8, w0v = (t >> 4) * 8;
  u16x8 vv[8];
#pragma unroll
  for (int i = 0; i < 8; ++i)
    vv[i] = *(const u16x8*)&v_t[base + (g0 + i) * 128 + w0v];
#pragma unroll
  for (int j = 0; j < 8; ++j) {
    int lin = j * 256 + t;
    int r = lin >> 4, c0 = (lin & 15) << 3;
    *(u16x8*)&Ks[r * LDK + c0] = *(const u16x8*)&k_t[base + lin * 8];
  }
  __syncthreads();

  // S^T[g][h]: A = Ks rows g, B = Q frags
  f32x4 acc[8][2];
#pragma unroll
  for (int mt = 0; mt < 8; ++mt) {
    acc[mt][0] = (f32x4){0.f, 0.f, 0.f, 0.f};
    acc[mt][1] = (f32x4){0.f, 0.f, 0.f, 0.f};
  }
#pragma unroll
  for (int kk = 0; kk < 4; ++kk) {
    int ko = kk * 32 + lq * 8;
#pragma unroll
    for (int mt = 0; mt < 8; ++mt) {
      bf16x8 a = *(const bf16x8*)&Ks[(mt * 16 + lrow) * LDK + ko];
      acc[mt][0] = MFMA(a, q0[kk], acc[mt][0]);
      acc[mt][1] = MFMA(a, q1[kk], acc[mt][1]);
    }
  }

  // softmax over g (rows of S^T): per-lane 32 values + quad combine via shfl_xor 16/32
  float inv[2];
#pragma unroll
  for (int nt = 0; nt < 2; ++nt) {
    float mx = -1e30f;
#pragma unroll
    for (int mt = 0; mt < 8; ++mt)
#pragma unroll
      for (int r = 0; r < 4; ++r) {
        acc[mt][nt][r] *= scl;
        mx = fmaxf(mx, acc[mt][nt][r]);
      }
    mx = fmaxf(mx, __shfl_xor(mx, 16));
    mx = fmaxf(mx, __shfl_xor(mx, 32));
    float s = 0.f;
#pragma unroll
    for (int mt = 0; mt < 8; ++mt)
#pragma unroll
      for (int r = 0; r < 4; ++r) {
        float e = __expf(acc[mt][nt][r] - mx);
        acc[mt][nt][r] = e;
        s += e;
      }
    s += __shfl_xor(s, 16);
    s += __shfl_xor(s, 32);
    inv[nt] = 1.f / s;
  }
  __syncthreads();   // all S-MFMA reads of Ks complete -> K dead

  // V^T into Ks (register 8x8 transpose); P into Ps [h][g]
#pragma unroll
  for (int j = 0; j < 8; ++j) {
    u16x8 tv;
#pragma unroll
    for (int i = 0; i < 8; ++i) tv[i] = vv[i][j];
    *(u16x8*)&Ks[(w0v + j) * LDK + g0] = tv;
  }
#pragma unroll
  for (int mt = 0; mt < 8; ++mt) {
    int gg0 = mt * 16 + lq * 4;
#pragma unroll
    for (int nt = 0; nt < 2; ++nt) {
      int hh = hstrip + nt * 16 + lrow;
      u16x4 p;
#pragma unroll
      for (int r = 0; r < 4; ++r) p[r] = f2b(acc[mt][nt][r] * inv[nt]);
      *(u16x4*)&Ps[hh * LDK + gg0] = p;
    }
  }
  __syncthreads();

  // O^T[w][h]: A = Ks(V^T) rows w, B = P rows h; direct store into q_t (own block region)
#pragma unroll
  for (int kk = 0; kk < 4; ++kk) {
    int ko = kk * 32 + lq * 8;
    bf16x8 b0 = *(const bf16x8*)&Ps[(hstrip + lrow) * LDK + ko];
    bf16x8 b1 = *(const bf16x8*)&Ps[(hstrip + 16 + lrow) * LDK + ko];
    if (kk == 0) {
#pragma unroll
      for (int mt = 0; mt < 8; ++mt) {
        acc[mt][0] = (f32x4){0.f, 0.f, 0.f, 0.f};
        acc[mt][1] = (f32x4){0.f, 0.f, 0.f, 0.f};
      }
    }
#pragma unroll
    for (int mt = 0; mt < 8; ++mt) {
      bf16x8 a = *(const bf16x8*)&Ks[(mt * 16 + lrow) * LDK + ko];
      acc[mt][0] = MFMA(a, b0, acc[mt][0]);
      acc[mt][1] = MFMA(a, b1, acc[mt][1]);
    }
  }
#pragma unroll
  for (int mt = 0; mt < 8; ++mt) {
    int w0i = mt * 16 + lq * 4;
#pragma unroll
    for (int nt = 0; nt < 2; ++nt) {
      int hh = hstrip + nt * 16 + lrow;
      u16x4 p;
#pragma unroll
      for (int r = 0; r < 4; ++r) p[r] = f2b(acc[mt][nt][r]);
      *(u16x4*)&q_t[base + hh * 128 + w0i] = p;
    }
  }
}

// ---------------- final: s = o @ Ws + bs; sigmoid; BN; out = x1 + x2*g (fp32) ----------------
// Ws^T fragments from global/L2 -> LDS = 36 KB -> 4 blocks/CU
__global__ __launch_bounds__(256, 4)
void final_kernel(const u16* __restrict__ o_t, const u16* __restrict__ wsT,
                  const float* __restrict__ x1, const float* __restrict__ x2,
                  const float* __restrict__ bs, const float* __restrict__ gamma,
                  const float* __restrict__ beta, const float* __restrict__ mu,
                  const float* __restrict__ var, float* __restrict__ out) {
  __shared__ u16 Os[128 * LDK];   // o^T tile [w][c]; later g' stage [w][d]
  __shared__ float bnA[128], bnB[128], bsf[128];

  const int t = threadIdx.x;
  const int bh = blockIdx.x;
  const int b = bh >> 7, h = bh & 127;
  const size_t obase = (size_t)b * 2097152 + (size_t)h * 128;
  const size_t pixbase = (size_t)bh * 16384;

  if (t < 128) {
    float a = gamma[t] * rsqrtf(var[t] + 1e-3f);
    bnA[t] = a;
    bnB[t] = beta[t] - mu[t] * a;
    bsf[t] = bs[t];
  }
  {  // transpose-load o tile -> Os[w][c]
    int c0 = (t & 15) * 8, w0 = (t >> 4) * 8;
    u16 ov[8][8];
#pragma unroll
    for (int i = 0; i < 8; ++i)
      *(u16x8*)&ov[i][0] = *(const u16x8*)&o_t[obase + (size_t)(c0 + i) * 16384 + w0];
#pragma unroll
    for (int j = 0; j < 8; ++j) {
      u16x8 tv;
#pragma unroll
      for (int i = 0; i < 8; ++i) tv[i] = ov[i][j];
      *(u16x8*)&Os[(w0 + j) * LDK + c0] = tv;
    }
  }
  __syncthreads();

  const int lane = t & 63, wave = t >> 6;
  const int lrow = lane & 15, lq = lane >> 4;
  const int wstrip = wave * 32;

  // D[d][w] = sum_c WsT[d][c] * Os[w][c]; A fragments straight from global (L2-hot)
  f32x4 acc[8][2];
#pragma unroll
  for (int mt = 0; mt < 8; ++mt) {
    acc[mt][0] = (f32x4){0.f, 0.f, 0.f, 0.f};
    acc[mt][1] = (f32x4){0.f, 0.f, 0.f, 0.f};
  }
#pragma unroll
  for (int kk = 0; kk < 4; ++kk) {
    int ko = kk * 32 + lq * 8;
    bf16x8 b0 = *(const bf16x8*)&Os[(wstrip + lrow) * LDK + ko];
    bf16x8 b1 = *(const bf16x8*)&Os[(wstrip + 16 + lrow) * LDK + ko];
#pragma unroll
    for (int mt = 0; mt < 8; ++mt) {
      bf16x8 a = *(const bf16x8*)&wsT[(mt * 16 + lrow) * 128 + ko];
      acc[mt][0] = MFMA(a, b0, acc[mt][0]);
      acc[mt][1] = MFMA(a, b1, acc[mt][1]);
    }
  }
  __syncthreads();  // all waves done reading Os -> reuse as stage

  // epilogue: sigmoid + BN, stage g' into Os[w][d]
#pragma unroll
  for (int mt = 0; mt < 8; ++mt) {
    int d0 = mt * 16 + lq * 4;
#pragma unroll
    for (int nt = 0; nt < 2; ++nt) {
      int w = wstrip + nt * 16 + lrow;
      u16x4 p;
#pragma unroll
      for (int r = 0; r < 4; ++r) {
        int d = d0 + r;
        float sv = acc[mt][nt][r] + bsf[d];
        float sg = 1.f / (1.f + __expf(-sv));
        p[r] = f2b(bnA[d] * sg + bnB[d]);
      }
      *(u16x4*)&Os[w * LDK + d0] = p;
    }
  }
  __syncthreads();

  {  // gated residual in fp32
    int w = t >> 1, d0 = (t & 1) * 64;
#pragma unroll
    for (int j = 0; j < 8; ++j) {
      int d = d0 + j * 8;
      u16x8 g8 = *(const u16x8*)&Os[w * LDK + d];
      f32x4 a0 = *(const f32x4*)&x1[pixbase + w * 128 + d];
      f32x4 a1 = *(const f32x4*)&x1[pixbase + w * 128 + d + 4];
      f32x4 c0v = *(const f32x4*)&x2[pixbase + w * 128 + d];
      f32x4 c1v = *(const f32x4*)&x2[pixbase + w * 128 + d + 4];
      f32x4 r0, r1;
#pragma unroll
      for (int i = 0; i < 4; ++i) {
        r0[i] = a0[i] + c0v[i] * b2f(g8[i]);
        r1[i] = a1[i] + c1v[i] * b2f(g8[4 + i]);
      }
      *(f32x4*)&out[pixbase + w * 128 + d] = r0;
      *(f32x4*)&out[pixbase + w * 128 + d + 4] = r1;
    }
  }
}

extern "C" void kernel_launch(void* const* d_in, const int* in_sizes, int n_in,
                              void* d_out, int out_size, void* d_ws, size_t ws_size,
                              hipStream_t stream) {
  const float* x1 = (const float*)d_in[0];
  const float* x2 = (const float*)d_in[1];
  const float* Wq = (const float*)d_in[2];
  const float* Wk = (const float*)d_in[3];
  const float* Wv = (const float*)d_in[4];
  const float* Ws = (const float*)d_in[5];
  const float* bs = (const float*)d_in[6];
  const float* scale = (const float*)d_in[7];
  const float* gamma = (const float*)d_in[8];
  const float* beta = (const float*)d_in[9];
  const float* mu = (const float*)d_in[10];
  const float* var = (const float*)d_in[11];
  float* outp = (float*)d_out;

  // workspace (bf16 elems): q_t | k_t | v_t : [B][C][H][W], then 4 transposed weights
  u16* q_t = (u16*)d_ws;
  u16* k_t = q_t + 16777216;
  u16* v_t = k_t + 16777216;
  u16* wT = v_t + 16777216;  // 4 * 16384

  wprep<<<dim3(4), dim3(256), 0, stream>>>(Wq, Wk, Wv, Ws, wT);
  qkv_kernel<<<dim3(1024, 3), dim3(256), 0, stream>>>(x1, x2, wT, q_t, k_t, v_t);
  attn_kernel<<<dim3(1024), dim3(256), 0, stream>>>(q_t, k_t, v_t, scale);
  final_kernel<<<dim3(1024), dim3(256), 0, stream>>>(q_t, wT + 3 * 16384, x1, x2, bs,
                                                     gamma, beta, mu, var, outp);
}